// Round 5
// baseline (257.361 us; speedup 1.0000x reference)
//
#include <hip/hip_runtime.h>

#define BATCH 8
#define NPTS 2048
#define BLOCKS_PER_BATCH 128
#define ROWS_PER_BLOCK 16   // NPTS / BLOCKS_PER_BATCH
#define WS_STRIDE 20        // 18 payload floats padded to 5 x float4
#define CNT_BYTE_OFF (BATCH * BLOCKS_PER_BATCH * WS_STRIDE * 4)   // counters after partials (81920)

// clang ext_vector (HIP's float4 is a struct; __builtin_nontemporal_load needs a scalar/vector type)
typedef float f4 __attribute__((ext_vector_type(4)));

// ---- counter zeroing: plain kernel launch, graph-capture-safe (R5: replaces
// the hipMemsetAsync that coincided with R4's container failure). ws is
// re-poisoned every iteration, so the zeroing must run every iteration.
__global__ void zero_cnt_kernel(unsigned int* __restrict__ cnt) {
    if (threadIdx.x < BATCH) cnt[threadIdx.x] = 0u;
}

// ---------------- single fused kernel ----------------------------------------
// Streaming pass over M (column-accumulation form):
//   S[d,e] = sum_k P[k,d] * T[k,e],  T[k,e] = sum_n M[n,k] * Q[n,e]
//   sum_matched[d] = sum_k P[k,d] * colsum[k]
// Each block owns ROWS_PER_BLOCK rows x all 2048 columns; thread t owns float4
// column groups {t, t+256}. 18-value block reduction (12 cov partials + 3
// P-col-sums + 3 Q-row-sums) -> ws. Then last-block-done: the 128th block of
// each batch acquires the partials and runs the 3x3 polar solve inline,
// overlapping finalize of batch b with streaming of later batches and killing
// the second kernel launch + full-grid drain barrier.
// No spin-waits anywhere -> no co-residency assumption, cannot deadlock (G16).
// NOTE (R1): no __launch_bounds__ min-waves — forcing VGPR<=64 spilled 235 B/thr
// (WRITE_SIZE 123 MB). NOTE (R3): hot loop stays unroll 4 — unroll 8 crosses the
// 128-VGPR occupancy cliff.
__global__ void __launch_bounds__(256) fused_kernel(
        const float* __restrict__ P, const float* __restrict__ Q,
        const float* __restrict__ M, float* __restrict__ ws,
        unsigned int* __restrict__ cnt, float* __restrict__ out) {
    __shared__ float sQ[ROWS_PER_BLOCK * 3];
    __shared__ float partial[4][18];
    __shared__ float redS[2][18];
    __shared__ int sLast;

    const int b = blockIdx.x >> 7;           // BLOCKS_PER_BATCH = 128
    const int blkInB = blockIdx.x & 127;
    const int n0 = blkInB * ROWS_PER_BLOCK;
    const float* Pb = P + b * NPTS * 3;
    const float* Qb = Q + b * NPTS * 3;
    const float* Mb = M + (size_t)b * NPTS * NPTS;

    const int t = threadIdx.x;
    if (t < ROWS_PER_BLOCK * 3) sQ[t] = Qb[n0 * 3 + t];
    __syncthreads();

    // accumulators: 2 column groups x 4 cols x (T[3] + colsum) = 32 regs
    float T0[4][3] = {}, T1[4][3] = {};
    float cs0[4] = {}, cs1[4] = {};

    const f4* Mrow0 = reinterpret_cast<const f4*>(Mb + (size_t)n0 * NPTS) + t;
    const f4* Mrow1 = Mrow0 + 256;

#pragma unroll 4
    for (int r = 0; r < ROWS_PER_BLOCK; ++r) {
        // M is read exactly once -> non-temporal hint (don't pollute L2/L3)
        const f4 m0 = __builtin_nontemporal_load(Mrow0 + (size_t)r * 512);  // row stride = 512 f4
        const f4 m1 = __builtin_nontemporal_load(Mrow1 + (size_t)r * 512);
        const float q0 = sQ[r * 3 + 0];
        const float q1 = sQ[r * 3 + 1];
        const float q2 = sQ[r * 3 + 2];
        T0[0][0] += m0.x * q0; T0[0][1] += m0.x * q1; T0[0][2] += m0.x * q2; cs0[0] += m0.x;
        T0[1][0] += m0.y * q0; T0[1][1] += m0.y * q1; T0[1][2] += m0.y * q2; cs0[1] += m0.y;
        T0[2][0] += m0.z * q0; T0[2][1] += m0.z * q1; T0[2][2] += m0.z * q2; cs0[2] += m0.z;
        T0[3][0] += m0.w * q0; T0[3][1] += m0.w * q1; T0[3][2] += m0.w * q2; cs0[3] += m0.w;
        T1[0][0] += m1.x * q0; T1[0][1] += m1.x * q1; T1[0][2] += m1.x * q2; cs1[0] += m1.x;
        T1[1][0] += m1.y * q0; T1[1][1] += m1.y * q1; T1[1][2] += m1.y * q2; cs1[1] += m1.y;
        T1[2][0] += m1.z * q0; T1[2][1] += m1.z * q1; T1[2][2] += m1.z * q2; cs1[2] += m1.z;
        T1[3][0] += m1.w * q0; T1[3][1] += m1.w * q1; T1[3][2] += m1.w * q2; cs1[3] += m1.w;
    }

    // acc layout: [0..8] S_raw, [9..11] sum_matched, [12..14] full-batch P sums
    // (bit-identical in every block -> x128 exactly, divided out exactly),
    // [15..17] this block's 16-row Q sum.
    float acc[18];
#pragma unroll
    for (int i = 0; i < 18; ++i) acc[i] = 0.0f;
    {
        const int k0 = 4 * t;
        const int k1 = 4 * (t + 256);
        const float* p0 = Pb + k0 * 3;
        const float* p1 = Pb + k1 * 3;
#pragma unroll
        for (int j = 0; j < 4; ++j) {
            const float pd0 = p0[j * 3 + 0], pd1 = p0[j * 3 + 1], pd2 = p0[j * 3 + 2];
#pragma unroll
            for (int e = 0; e < 3; ++e) {
                acc[0 + e] += pd0 * T0[j][e];
                acc[3 + e] += pd1 * T0[j][e];
                acc[6 + e] += pd2 * T0[j][e];
            }
            acc[9]  += pd0 * cs0[j];
            acc[10] += pd1 * cs0[j];
            acc[11] += pd2 * cs0[j];
            acc[12] += pd0; acc[13] += pd1; acc[14] += pd2;
        }
#pragma unroll
        for (int j = 0; j < 4; ++j) {
            const float pd0 = p1[j * 3 + 0], pd1 = p1[j * 3 + 1], pd2 = p1[j * 3 + 2];
#pragma unroll
            for (int e = 0; e < 3; ++e) {
                acc[0 + e] += pd0 * T1[j][e];
                acc[3 + e] += pd1 * T1[j][e];
                acc[6 + e] += pd2 * T1[j][e];
            }
            acc[9]  += pd0 * cs1[j];
            acc[10] += pd1 * cs1[j];
            acc[11] += pd2 * cs1[j];
            acc[12] += pd0; acc[13] += pd1; acc[14] += pd2;
        }
    }
    if (t < ROWS_PER_BLOCK) {
        acc[15] = sQ[t * 3 + 0];
        acc[16] = sQ[t * 3 + 1];
        acc[17] = sQ[t * 3 + 2];
    }

    // block reduction of 18 values: wave butterfly, then LDS across 4 waves
#pragma unroll
    for (int off = 32; off > 0; off >>= 1) {
#pragma unroll
        for (int i = 0; i < 18; ++i) acc[i] += __shfl_xor(acc[i], off);
    }
    const int wave = t >> 6;
    const int lane = t & 63;
    if (lane == 0) {
#pragma unroll
        for (int i = 0; i < 18; ++i) partial[wave][i] = acc[i];
    }
    __syncthreads();
    if (t < 18) {
        float v = partial[0][t] + partial[1][t] + partial[2][t] + partial[3][t];
        ws[(size_t)blockIdx.x * WS_STRIDE + t] = v;   // per-block partial
    }

    // ---- last-block-done handoff (device-scope: partials cross XCD L2s) ----
    __threadfence();                 // release: push partial stores device-visible
    __syncthreads();                 // order all threads' stores before the atomic
    if (t == 0) {
        unsigned int old = atomicAdd(&cnt[b], 1u);   // device-scope by default
        sLast = (old == BLOCKS_PER_BATCH - 1);
    }
    __syncthreads();
    if (!sLast) return;
    __threadfence();                 // acquire: invalidate stale cached partials

    // ---- final reduction of this batch's 128 partials (threads 0..127) ----
    if (t < BLOCKS_PER_BATCH) {
        const f4* p4 = reinterpret_cast<const f4*>(
            ws + ((size_t)b * BLOCKS_PER_BATCH + t) * WS_STRIDE);
        f4 a = p4[0], c = p4[1], d = p4[2], e = p4[3], f = p4[4];
        float v[18] = { a.x, a.y, a.z, a.w, c.x, c.y, c.z, c.w,
                        d.x, d.y, d.z, d.w, e.x, e.y, e.z, e.w, f.x, f.y };
#pragma unroll
        for (int off = 32; off > 0; off >>= 1) {
#pragma unroll
            for (int i = 0; i < 18; ++i) v[i] += __shfl_xor(v[i], off);
        }
        if (lane == 0) {
#pragma unroll
            for (int i = 0; i < 18; ++i) redS[wave][i] = v[i];
        }
    }
    __syncthreads();

    if (t == 0) {
        double w[18];
        for (int i = 0; i < 18; ++i) w[i] = (double)redS[0][i] + (double)redS[1][i];

        const double sp[3] = { w[12] * (1.0 / 128.0), w[13] * (1.0 / 128.0), w[14] * (1.0 / 128.0) };
        const double sq[3] = { w[15], w[16], w[17] };

        // S[d][e] = S_raw[d][e] - sum_matched[d]*sum_Q[e]/N
        double Sm[9];
        for (int d = 0; d < 3; ++d)
            for (int e = 0; e < 3; ++e)
                Sm[d * 3 + e] = w[d * 3 + e] - w[9 + d] * sq[e] / (double)NPTS;

        // R = polar factor of A = S^T (scaled Newton, 8 iters — verified margin)
        double X[9];
        for (int i = 0; i < 3; ++i)
            for (int j = 0; j < 3; ++j)
                X[i * 3 + j] = Sm[j * 3 + i];
        for (int iter = 0; iter < 8; ++iter) {
            double a0 = X[0], a1 = X[1], a2 = X[2];
            double a3 = X[3], a4 = X[4], a5 = X[5];
            double a6 = X[6], a7 = X[7], a8 = X[8];
            double c0 = a4 * a8 - a5 * a7;
            double c1 = a5 * a6 - a3 * a8;
            double c2 = a3 * a7 - a4 * a6;
            double det = a0 * c0 + a1 * c1 + a2 * c2;
            double invdet = 1.0 / det;
            double inv[9];
            inv[0] = c0 * invdet; inv[1] = (a2 * a7 - a1 * a8) * invdet; inv[2] = (a1 * a5 - a2 * a4) * invdet;
            inv[3] = c1 * invdet; inv[4] = (a0 * a8 - a2 * a6) * invdet; inv[5] = (a2 * a3 - a0 * a5) * invdet;
            inv[6] = c2 * invdet; inv[7] = (a1 * a6 - a0 * a7) * invdet; inv[8] = (a0 * a4 - a1 * a3) * invdet;
            double fx = 0, fi = 0;
            for (int i = 0; i < 9; ++i) { fx += X[i] * X[i]; fi += inv[i] * inv[i]; }
            double g = sqrt(sqrt(fi / fx));
            double Xn[9];
            for (int i = 0; i < 3; ++i)
                for (int j = 0; j < 3; ++j)
                    Xn[i * 3 + j] = 0.5 * (g * X[i * 3 + j] + inv[j * 3 + i] / g);
            for (int i = 0; i < 9; ++i) X[i] = Xn[i];
        }
        for (int i = 0; i < 9; ++i) out[b * 9 + i] = (float)X[i];
        const double mpx = sp[0] / NPTS, mpy = sp[1] / NPTS, mpz = sp[2] / NPTS;
        for (int d = 0; d < 3; ++d) {
            double td = sq[d] / NPTS - (X[d * 3 + 0] * mpx + X[d * 3 + 1] * mpy + X[d * 3 + 2] * mpz);
            out[BATCH * 9 + b * 3 + d] = (float)td;
        }
    }
}

extern "C" void kernel_launch(void* const* d_in, const int* in_sizes, int n_in,
                              void* d_out, int out_size, void* d_ws, size_t ws_size,
                              hipStream_t stream) {
    const float* P = (const float*)d_in[0];   // Ppc [8,2048,3] f32
    const float* Q = (const float*)d_in[1];   // Qpc [8,2048,3] f32
    const float* M = (const float*)d_in[2];   // M   [8,2048,2048] f32
    float* out = (float*)d_out;               // R [8,3,3] ++ t [8,3] = 96 f32
    float* ws = (float*)d_ws;                 // partials: 1024*20 f32 = 80 KB, then 8 counters
    unsigned int* cnt = (unsigned int*)((char*)d_ws + CNT_BYTE_OFF);

    zero_cnt_kernel<<<1, 64, 0, stream>>>(cnt);
    fused_kernel<<<BATCH * BLOCKS_PER_BATCH, 256, 0, stream>>>(P, Q, M, ws, cnt, out);
}

// Round 6
// 193.312 us; speedup vs baseline: 1.3313x; 1.3313x over previous
//
#include <hip/hip_runtime.h>

#define BATCH 8
#define NPTS 2048
#define BLOCKS_PER_BATCH 128
#define ROWS_PER_BLOCK 16   // NPTS / BLOCKS_PER_BATCH
#define WS_STRIDE 20        // 18 payload floats padded to 5 x float4

// clang ext_vector (HIP's float4 is a struct; __builtin_nontemporal_load needs a scalar/vector type)
typedef float f4 __attribute__((ext_vector_type(4)));

// ---------------- kernel 1: streaming pass over M (column-accumulation form) ----
// S[d,e] = sum_k P[k,d] * T[k,e],  T[k,e] = sum_n M[n,k] * Q[n,e]
// sum_matched[d] = sum_k P[k,d] * colsum[k]
// Each block owns ROWS_PER_BLOCK rows x all 2048 columns. Thread t owns float4
// column groups {t, t+256}. Zero cross-lane traffic in the hot loop; one
// 18-value block reduction at the end (12 covariance partials + 3 P-col-sums
// + 3 Q-row-sums, so finalize never re-reads P/Q); partials to ws.
// NOTE (R1): do NOT force min-waves via __launch_bounds__(256,8) — capped VGPR
// at 64, spilled 235 B/thread (WRITE_SIZE 123 MB, 3.0 TB/s effective).
// NOTE (R3): hot loop stays unroll 4 — unroll 8 crosses the 128-VGPR cliff.
// NOTE (R5): do NOT fuse the f64 polar solve into this kernel — the cold f64
// tail drove regalloc to 44 VGPRs, serialized the load pipeline (660 GB/s,
// 102 us). Two kernels is the stable optimum.
__global__ void __launch_bounds__(256) cross_cov_kernel(
        const float* __restrict__ P, const float* __restrict__ Q,
        const float* __restrict__ M, float* __restrict__ ws) {
    __shared__ float sQ[ROWS_PER_BLOCK * 3];
    __shared__ float partial[4][18];

    const int b = blockIdx.x >> 7;           // BLOCKS_PER_BATCH = 128
    const int blkInB = blockIdx.x & 127;
    const int n0 = blkInB * ROWS_PER_BLOCK;
    const float* Pb = P + b * NPTS * 3;
    const float* Qb = Q + b * NPTS * 3;
    const float* Mb = M + (size_t)b * NPTS * NPTS;

    const int t = threadIdx.x;
    if (t < ROWS_PER_BLOCK * 3) sQ[t] = Qb[n0 * 3 + t];
    __syncthreads();

    // accumulators: 2 column groups x 4 cols x (T[3] + colsum) = 32 regs
    float T0[4][3] = {}, T1[4][3] = {};
    float cs0[4] = {}, cs1[4] = {};

    const f4* Mrow0 = reinterpret_cast<const f4*>(Mb + (size_t)n0 * NPTS) + t;
    const f4* Mrow1 = Mrow0 + 256;

#pragma unroll 4
    for (int r = 0; r < ROWS_PER_BLOCK; ++r) {
        // M is read exactly once -> non-temporal hint (don't pollute L2/L3)
        const f4 m0 = __builtin_nontemporal_load(Mrow0 + (size_t)r * 512);  // row stride = 2048 f = 512 f4
        const f4 m1 = __builtin_nontemporal_load(Mrow1 + (size_t)r * 512);
        const float q0 = sQ[r * 3 + 0];
        const float q1 = sQ[r * 3 + 1];
        const float q2 = sQ[r * 3 + 2];
        T0[0][0] += m0.x * q0; T0[0][1] += m0.x * q1; T0[0][2] += m0.x * q2; cs0[0] += m0.x;
        T0[1][0] += m0.y * q0; T0[1][1] += m0.y * q1; T0[1][2] += m0.y * q2; cs0[1] += m0.y;
        T0[2][0] += m0.z * q0; T0[2][1] += m0.z * q1; T0[2][2] += m0.z * q2; cs0[2] += m0.z;
        T0[3][0] += m0.w * q0; T0[3][1] += m0.w * q1; T0[3][2] += m0.w * q2; cs0[3] += m0.w;
        T1[0][0] += m1.x * q0; T1[0][1] += m1.x * q1; T1[0][2] += m1.x * q2; cs1[0] += m1.x;
        T1[1][0] += m1.y * q0; T1[1][1] += m1.y * q1; T1[1][2] += m1.y * q2; cs1[1] += m1.y;
        T1[2][0] += m1.z * q0; T1[2][1] += m1.z * q1; T1[2][2] += m1.z * q2; cs1[2] += m1.z;
        T1[3][0] += m1.w * q0; T1[3][1] += m1.w * q1; T1[3][2] += m1.w * q2; cs1[3] += m1.w;
    }

    // acc layout: [0..8] S_raw, [9..11] sum_matched, [12..14] P column sums
    // (every block computes the full-batch P sum -> bit-identical across the
    // 128 blocks; finalize divides by 128, exact), [15..17] this block's
    // 16-row Q sum (sums correctly over blocks).
    float acc[18];
#pragma unroll
    for (int i = 0; i < 18; ++i) acc[i] = 0.0f;
    {
        const int k0 = 4 * t;
        const int k1 = 4 * (t + 256);
        const float* p0 = Pb + k0 * 3;     // 12 consecutive floats, 16B-aligned
        const float* p1 = Pb + k1 * 3;
#pragma unroll
        for (int j = 0; j < 4; ++j) {
            const float pd0 = p0[j * 3 + 0], pd1 = p0[j * 3 + 1], pd2 = p0[j * 3 + 2];
#pragma unroll
            for (int e = 0; e < 3; ++e) {
                acc[0 + e] += pd0 * T0[j][e];
                acc[3 + e] += pd1 * T0[j][e];
                acc[6 + e] += pd2 * T0[j][e];
            }
            acc[9]  += pd0 * cs0[j];
            acc[10] += pd1 * cs0[j];
            acc[11] += pd2 * cs0[j];
            acc[12] += pd0; acc[13] += pd1; acc[14] += pd2;
        }
#pragma unroll
        for (int j = 0; j < 4; ++j) {
            const float pd0 = p1[j * 3 + 0], pd1 = p1[j * 3 + 1], pd2 = p1[j * 3 + 2];
#pragma unroll
            for (int e = 0; e < 3; ++e) {
                acc[0 + e] += pd0 * T1[j][e];
                acc[3 + e] += pd1 * T1[j][e];
                acc[6 + e] += pd2 * T1[j][e];
            }
            acc[9]  += pd0 * cs1[j];
            acc[10] += pd1 * cs1[j];
            acc[11] += pd2 * cs1[j];
            acc[12] += pd0; acc[13] += pd1; acc[14] += pd2;
        }
    }
    // this block's Q-row sums: rows n0..n0+15 live in sQ; lanes 0..15 (wave 0)
    // contribute one row each, the butterfly sums them.
    if (t < ROWS_PER_BLOCK) {
        acc[15] = sQ[t * 3 + 0];
        acc[16] = sQ[t * 3 + 1];
        acc[17] = sQ[t * 3 + 2];
    }

    // block reduction of 18 values: wave butterfly (once per block), then LDS
#pragma unroll
    for (int off = 32; off > 0; off >>= 1) {
#pragma unroll
        for (int i = 0; i < 18; ++i) acc[i] += __shfl_xor(acc[i], off);
    }
    const int wave = t >> 6;
    const int lane = t & 63;
    if (lane == 0) {
#pragma unroll
        for (int i = 0; i < 18; ++i) partial[wave][i] = acc[i];
    }
    __syncthreads();
    if (t < 18) {
        float v = partial[0][t] + partial[1][t] + partial[2][t] + partial[3][t];
        ws[(size_t)blockIdx.x * WS_STRIDE + t] = v;   // per-block partial, no atomics
    }
}

// ---------------- kernel 2: reduce partials + 3x3 polar -> R, t ----------
// Reads ONLY ws (10 KB/batch, L2-hot): P/Q sums were folded into kernel 1.
__global__ void __launch_bounds__(256) finalize_kernel(
        const float* __restrict__ ws, float* __restrict__ out) {
    const int b = blockIdx.x;
    const int t = threadIdx.x;
    const int wave = t >> 6;
    const int lane = t & 63;

    __shared__ float redS[2][18];

    // ---- reduce the 128 per-block partials of this batch (threads 0..127) ----
    if (t < BLOCKS_PER_BATCH) {
        const f4* p4 = reinterpret_cast<const f4*>(
            ws + ((size_t)b * BLOCKS_PER_BATCH + t) * WS_STRIDE);
        f4 a = p4[0], c = p4[1], d = p4[2], e = p4[3], f = p4[4];
        float v[18] = { a.x, a.y, a.z, a.w, c.x, c.y, c.z, c.w,
                        d.x, d.y, d.z, d.w, e.x, e.y, e.z, e.w, f.x, f.y };
#pragma unroll
        for (int off = 32; off > 0; off >>= 1) {
#pragma unroll
            for (int i = 0; i < 18; ++i) v[i] += __shfl_xor(v[i], off);
        }
        if (lane == 0) {
#pragma unroll
            for (int i = 0; i < 18; ++i) redS[wave][i] = v[i];
        }
    }
    __syncthreads();

    if (t == 0) {
        double w[18];
        for (int i = 0; i < 18; ++i) w[i] = (double)redS[0][i] + (double)redS[1][i];

        // P sums were written identically by all 128 blocks: tree-summed 128x,
        // exact power-of-2 multiple -> divide back out exactly.
        const double sp[3] = { w[12] * (1.0 / 128.0), w[13] * (1.0 / 128.0), w[14] * (1.0 / 128.0) };
        const double sq[3] = { w[15], w[16], w[17] };

        // S[d][e] = S_raw[d][e] - sum_matched[d]*sum_Q[e]/N
        double Sm[9];
        for (int d = 0; d < 3; ++d)
            for (int e = 0; e < 3; ++e)
                Sm[d * 3 + e] = w[d * 3 + e] - w[9 + d] * sq[e] / (double)NPTS;

        // R = polar factor of A = S^T (scaled Newton, 8 iters — verified margin)
        double X[9];
        for (int i = 0; i < 3; ++i)
            for (int j = 0; j < 3; ++j)
                X[i * 3 + j] = Sm[j * 3 + i];
        for (int iter = 0; iter < 8; ++iter) {
            double a0 = X[0], a1 = X[1], a2 = X[2];
            double a3 = X[3], a4 = X[4], a5 = X[5];
            double a6 = X[6], a7 = X[7], a8 = X[8];
            double c0 = a4 * a8 - a5 * a7;
            double c1 = a5 * a6 - a3 * a8;
            double c2 = a3 * a7 - a4 * a6;
            double det = a0 * c0 + a1 * c1 + a2 * c2;
            double invdet = 1.0 / det;
            double inv[9];
            inv[0] = c0 * invdet; inv[1] = (a2 * a7 - a1 * a8) * invdet; inv[2] = (a1 * a5 - a2 * a4) * invdet;
            inv[3] = c1 * invdet; inv[4] = (a0 * a8 - a2 * a6) * invdet; inv[5] = (a2 * a3 - a0 * a5) * invdet;
            inv[6] = c2 * invdet; inv[7] = (a1 * a6 - a0 * a7) * invdet; inv[8] = (a0 * a4 - a1 * a3) * invdet;
            double fx = 0, fi = 0;
            for (int i = 0; i < 9; ++i) { fx += X[i] * X[i]; fi += inv[i] * inv[i]; }
            double g = sqrt(sqrt(fi / fx));
            double Xn[9];
            for (int i = 0; i < 3; ++i)
                for (int j = 0; j < 3; ++j)
                    Xn[i * 3 + j] = 0.5 * (g * X[i * 3 + j] + inv[j * 3 + i] / g);
            for (int i = 0; i < 9; ++i) X[i] = Xn[i];
        }
        for (int i = 0; i < 9; ++i) out[b * 9 + i] = (float)X[i];
        const double mpx = sp[0] / NPTS, mpy = sp[1] / NPTS, mpz = sp[2] / NPTS;
        for (int d = 0; d < 3; ++d) {
            double td = sq[d] / NPTS - (X[d * 3 + 0] * mpx + X[d * 3 + 1] * mpy + X[d * 3 + 2] * mpz);
            out[BATCH * 9 + b * 3 + d] = (float)td;
        }
    }
}

extern "C" void kernel_launch(void* const* d_in, const int* in_sizes, int n_in,
                              void* d_out, int out_size, void* d_ws, size_t ws_size,
                              hipStream_t stream) {
    const float* P = (const float*)d_in[0];   // Ppc [8,2048,3] f32
    const float* Q = (const float*)d_in[1];   // Qpc [8,2048,3] f32
    const float* M = (const float*)d_in[2];   // M   [8,2048,2048] f32
    float* out = (float*)d_out;               // R [8,3,3] ++ t [8,3] = 96 f32
    float* ws = (float*)d_ws;                 // per-block partials: 1024*20 f32 = 80 KB

    cross_cov_kernel<<<BATCH * BLOCKS_PER_BATCH, 256, 0, stream>>>(P, Q, M, ws);
    finalize_kernel<<<BATCH, 256, 0, stream>>>(ws, out);
}